// Round 7
// baseline (55.325 us; speedup 1.0000x reference)
//
#include <hip/hip_runtime.h>

// DistributedMemory forward:
//   inputs[b,:] = P[doc_ids[b],:] + sum_c W[context_ids[b,c],:]      [B,128]
//   out[b,s]    = dot(inputs[b,:], outputs[:, sample_ids[b,s]])      [B,S]
// B=16384, C=8, S=10, D=128, N_WORDS=100000, N_DOCS=1e6. All f32.
//
// R6 -> R7: transpose structure is byte-bound at ~44 µs (3 variants within
// 1 µs). Return to the binned structure (reads `outs` exactly once, no
// 51MB+84MB transpose round-trip) with its R4 latency defects fixed:
//  - build+bin fused into one kernel (3 dispatches total incl. memset)
//  - serve: double-buffered LDS slab, ONE barrier per chunk, next chunk's
//    global loads issued before serving current (latency hidden under serve)
//  - inputs rows read directly from global (8.4MB hot, L2/L3) - no LDS
//    staging phase, no second barrier
//  - 4 threads/sample, 8x float4, 2-step shfl reduce

#define VEC_DIM 128
#define NW      100000
#define NW4     (NW / 4)         // 25000
#define CTX     8
#define NSAMP   10
#define WB      32               // words per chunk
#define NCHUNK  (NW / WB)        // 3125
#define CAP     256
#define TS      132              // slab row stride in floats (16B-aligned)
#define EGRID   1024             // serve grid (4 blocks/CU x 256 CU)

// -------- AB: inputs build (+ sample binning in spare threads) ------------
__global__ __launch_bounds__(256) void build_bin_kernel(
    const int* __restrict__ doc_ids,
    const int* __restrict__ context_ids,
    const int* __restrict__ sample_ids,
    const float* __restrict__ P,       // [N_DOCS,128]
    const float* __restrict__ W,       // [NW,128]
    float* __restrict__ inputs,        // [B,128]
    int* __restrict__ counts,          // [NCHUNK]
    int* __restrict__ list)            // [NCHUNK][CAP]
{
    const int t    = threadIdx.x;
    const int tsub = t & 31;
    const int b    = blockIdx.x * 8 + (t >> 5);

    const float4* __restrict__ P4 = (const float4*)P;
    const float4* __restrict__ W4 = (const float4*)W;

    float4 v = P4[doc_ids[b] * 32 + tsub];
    #pragma unroll
    for (int c = 0; c < CTX; ++c) {
        float4 w4 = W4[context_ids[b * CTX + c] * 32 + tsub];
        v.x += w4.x; v.y += w4.y; v.z += w4.z; v.w += w4.w;
    }
    ((float4*)inputs)[b * 32 + tsub] = v;

    // bin this block's 8 b's worth of samples (8*NSAMP = 80)
    if (t < 8 * NSAMP) {
        const int p = blockIdx.x * 8 * NSAMP + t;      // < 163840 < 2^18
        const int w = sample_ids[p];
        const int c = w >> 5;                          // WB = 32
        const int slot = atomicAdd(&counts[c], 1);
        if (slot < CAP)
            list[c * CAP + slot] = ((w & (WB - 1)) << 18) | p;
    }
}

// -------- E: double-buffered slab serve -----------------------------------
__global__ __launch_bounds__(256, 4) void serve_kernel(
    const float* __restrict__ outs,     // [128, NW]
    const float* __restrict__ inputs,   // [B,128]
    const int* __restrict__ counts,
    const int* __restrict__ list,
    float* __restrict__ out)            // [B*S]
{
    __shared__ float slab[2][WB * TS];  // 2 x 16,896 B = 33,792 B
    const int t = threadIdx.x;
    const float4* __restrict__ outs4 = (const float4*)outs;
    const float4* __restrict__ in4   = (const float4*)inputs;

    int ci = blockIdx.x;
    if (ci >= NCHUNK) return;

    // prologue: load first chunk's slab into registers
    float4 r0, r1, r2, r3;
    {
        const int u = t & 7;
        const int d0 = t >> 3;                    // base dim for i=0
        r0 = outs4[(d0 +  0) * NW4 + ci * 8 + u];
        r1 = outs4[(d0 + 32) * NW4 + ci * 8 + u];
        r2 = outs4[(d0 + 64) * NW4 + ci * 8 + u];
        r3 = outs4[(d0 + 96) * NW4 + ci * 8 + u];
    }

    int buf = 0;
    while (true) {
        // ---- write staged regs -> slab[buf] (transposed [w][d]) ----
        {
            const int u  = t & 7;
            const int d0 = t >> 3;
            float* dst = &slab[buf][0];
            #pragma unroll
            for (int j = 0; j < 4; ++j) {
                dst[(4*u + j) * TS + d0 +  0] = (&r0.x)[j];
                dst[(4*u + j) * TS + d0 + 32] = (&r1.x)[j];
                dst[(4*u + j) * TS + d0 + 64] = (&r2.x)[j];
                dst[(4*u + j) * TS + d0 + 96] = (&r3.x)[j];
            }
        }
        __syncthreads();   // slab[buf] ready; also fences serve of slab[buf^1]
                           // from the iteration before last (see R7 notes)

        // ---- issue next chunk's loads (latency hides under serve) ----
        const int cn = ci + EGRID;
        if (cn < NCHUNK) {
            const int u  = t & 7;
            const int d0 = t >> 3;
            r0 = outs4[(d0 +  0) * NW4 + cn * 8 + u];
            r1 = outs4[(d0 + 32) * NW4 + cn * 8 + u];
            r2 = outs4[(d0 + 64) * NW4 + cn * 8 + u];
            r3 = outs4[(d0 + 96) * NW4 + cn * 8 + u];
        }

        // ---- serve chunk ci from slab[buf] ----
        const int cnt = min(counts[ci], CAP);
        const float4* sl4 = (const float4*)&slab[buf][0];   // row stride 33 f4
        const int seg = t & 3;
        for (int i0 = 0; i0 < cnt; i0 += 64) {
            const int i = i0 + (t >> 2);
            if (i < cnt) {
                const int e = list[ci * CAP + i];
                const int p = e & 0x3FFFF;
                const int j = e >> 18;
                const unsigned bb = (unsigned)p / NSAMP;
                float ax = 0.f, ay = 0.f, az = 0.f, aw = 0.f;
                #pragma unroll
                for (int k = 0; k < 8; ++k) {
                    float4 a = in4[bb * 32 + seg * 8 + k];  // L2/L3-hot row
                    float4 o = sl4[j * 33  + seg * 8 + k];
                    ax += a.x * o.x; ay += a.y * o.y;
                    az += a.z * o.z; aw += a.w * o.w;
                }
                float s = (ax + ay) + (az + aw);
                s += __shfl_xor(s, 1, 64);
                s += __shfl_xor(s, 2, 64);
                if (seg == 0) out[p] = s;
            }
        }

        if (cn >= NCHUNK) break;
        ci = cn;
        buf ^= 1;
        // no barrier here: next write targets slab[buf^1]; its last readers
        // finished before the __syncthreads() above (program order).
    }
}

// -------- fallback (tiny ws): direct strided gather ----------------------
__global__ __launch_bounds__(128) void dm_fwd_direct(
    const int* __restrict__ doc_ids,
    const int* __restrict__ context_ids,
    const int* __restrict__ sample_ids,
    const float* __restrict__ P,
    const float* __restrict__ W,
    const float* __restrict__ outs,
    float* __restrict__ out)
{
    const int b = blockIdx.x;
    const int d = threadIdx.x;
    const int lane = d & 63;
    const int wave = d >> 6;

    float v = P[(long)doc_ids[b] * VEC_DIM + d];
    #pragma unroll
    for (int c = 0; c < CTX; ++c)
        v += W[(long)context_ids[b * CTX + c] * VEC_DIM + d];

    __shared__ float partial[2 * NSAMP];
    #pragma unroll
    for (int s = 0; s < NSAMP; ++s) {
        const int w = sample_ids[b * NSAMP + s];
        float p = v * outs[(long)d * NW + w];
        #pragma unroll
        for (int off = 32; off > 0; off >>= 1)
            p += __shfl_down(p, off, 64);
        if (lane == 0) partial[wave * NSAMP + s] = p;
    }
    __syncthreads();
    if (d < NSAMP) out[b * NSAMP + d] = partial[d] + partial[NSAMP + d];
}

extern "C" void kernel_launch(void* const* d_in, const int* in_sizes, int n_in,
                              void* d_out, int out_size, void* d_ws, size_t ws_size,
                              hipStream_t stream) {
    const int*   doc_ids     = (const int*)d_in[0];
    const int*   context_ids = (const int*)d_in[1];
    const int*   sample_ids  = (const int*)d_in[2];
    const float* P           = (const float*)d_in[3];
    const float* W           = (const float*)d_in[4];
    const float* outs        = (const float*)d_in[5];
    float*       out         = (float*)d_out;

    const int B = in_sizes[0];          // 16384

    const size_t off_inputs = 0;
    const size_t sz_inputs  = (size_t)B * VEC_DIM * sizeof(float);   // 8.4 MB
    const size_t off_counts = off_inputs + sz_inputs;
    const size_t sz_counts  = 65536;                                 // >= NCHUNK*4
    const size_t off_list   = off_counts + sz_counts;
    const size_t sz_list    = (size_t)NCHUNK * CAP * sizeof(int);    // 3.2 MB
    const size_t needed     = off_list + sz_list;

    if (ws_size >= needed && (B % 8) == 0) {
        float* inputs = (float*)((char*)d_ws + off_inputs);
        int*   counts = (int*)  ((char*)d_ws + off_counts);
        int*   list   = (int*)  ((char*)d_ws + off_list);

        hipMemsetAsync(counts, 0, NCHUNK * sizeof(int), stream);
        build_bin_kernel<<<B / 8, 256, 0, stream>>>(
            doc_ids, context_ids, sample_ids, P, W, inputs, counts, list);
        serve_kernel<<<EGRID, 256, 0, stream>>>(
            outs, inputs, counts, list, out);
    } else {
        dm_fwd_direct<<<B, 128, 0, stream>>>(doc_ids, context_ids, sample_ids,
                                             P, W, outs, out);
    }
}